// Round 2
// baseline (216.190 us; speedup 1.0000x reference)
//
#include <hip/hip_runtime.h>
#include <hip/hip_cooperative_groups.h>

namespace cg = cooperative_groups;

#define NB 32
#define NN 8400
#define NC 80
#define KPRE 512
#define MAXOUT 100
#define NWV 526              // 16-row wave-groups per image (525 real + 1 pad-handling)
#define NGROUPS (NB * NWV)   // 16832
#define GRID1 256            // cooperative grid: 1 block/CU (LDS-limited)

// ---------------- shared-memory plan: phase-1 staging and phase-2 structures are
// temporally disjoint (separated by grid sync / kernel boundary) -> union ----------------
struct P2 {
    unsigned histA[2048];               // 8 KB
    unsigned histB[2048];               // 8 KB
    unsigned long long list[KPRE];      // 4 KB   (16B aligned at offset 16384)
    unsigned long long sorted[KPRE];    // 4 KB
    unsigned long long elist64[256];    // 2 KB
    int srank[KPRE];                    // 2 KB
    float4 sb[KPRE];                    // 8 KB  offset boxes
    float4 sraw[KPRE];                  // 8 KB  raw boxes
    float4 smeta[KPRE];                 // 8 KB  (obj, cc, cp, valid)
    float sarea[KPRE];                  // 2 KB
    unsigned long long siou[KPRE * 8];  // 32 KB IoU bitmatrix
    unsigned long long skeep[8];
    int S_B[2];
    unsigned S_T[2];
    int S_cnt, S_ecnt, S_done;
    float S_conf;
    unsigned S_mbits;
};

union __align__(16) SMem {
    float4 stg[16][340];                // phase 1: 16 waves x (16 rows x 85 floats) = 87040 B
    P2 p2;                              // phase 2: ~88.2 KB
};

// ---------------- phase 1 (per wave, one 16-row group): scores + per-wave max ----------------
__device__ __forceinline__ void score_group(const float4* __restrict__ p4, int gg, int w, int lane,
                                            float4 (*stg)[340],
                                            float* __restrict__ scores,
                                            unsigned* __restrict__ wmaxg) {
    int b = gg / NWV, g = gg - b * NWV;
    size_t base4 = (size_t)b * 178500 + (size_t)g * 340;
    size_t img_end4 = ((size_t)b + 1) * 178500;
    for (int k = lane; k < 340; k += 64) {
        size_t e = base4 + k;
        if (e >= img_end4) e = img_end4 - 1;      // clamp tail (rows >= NN discarded below)
        stg[w][k] = p4[e];
    }
    // 4 lanes share a row: q scans classes 20q..20q+19 (value only; argmax redone at select)
    int rl = lane >> 2, q = lane & 3;
    int row = g * 16 + rl;
    const float* r = (const float*)&stg[w][0] + rl * 85;
    float obj = r[4];
    int c0 = 5 + q * 20;
    float cc = r[c0];
    for (int c = 1; c < 20; c++) {
        float v = r[c0 + c];
        if (v > cc) cc = v;
    }
    {
        float cc1 = __shfl_xor(cc, 1, 64); if (cc1 > cc) cc = cc1;
        float cc2 = __shfl_xor(cc, 2, 64); if (cc2 > cc) cc = cc2;
    }
    float s = __fmul_rn(obj, cc);
    // lane 4l holds row l's score; redistribute for one coalesced 16-lane store
    int srcl = (lane & 15) * 4;
    float v7 = __shfl(s, srcl, 64);
    int wrow = g * 16 + (lane & 15);
    if (lane < 16 && wrow < NN) scores[(size_t)b * NN + wrow] = v7;
    // per-wave max (invalid rows -> 0); every slot written -> no init needed
    if (row >= NN) s = 0.0f;
    unsigned bits = __float_as_uint(s);
    for (int o = 32; o > 0; o >>= 1) {
        unsigned other = (unsigned)__shfl_down((int)bits, o, 64);
        if (other > bits) bits = other;
    }
    if (lane == 0) wmaxg[gg] = bits;
}

// ---- wave-0 helper: largest bin B with suffix(B) >= T; R = T - suffix(B+1).
// Prefetches the next chunk's LDS row so the load hides under the 6-step shfl chain.
__device__ __forceinline__ void find_bin(const unsigned* hist, int cstart, unsigned T, int lane,
                                         int* outB, unsigned* outR) {
    unsigned running = 0;
    unsigned v = hist[cstart * 64 + lane];
    for (int c = cstart; c >= 0; c--) {
        unsigned vn = (c > 0) ? hist[(c - 1) * 64 + lane] : 0u;   // prefetch
        unsigned s = v;
        for (int off = 1; off < 64; off <<= 1) {
            unsigned u = (unsigned)__shfl_down((int)s, off, 64);
            if (lane + off < 64) s += u;
        }
        unsigned total0 = (unsigned)__shfl((int)s, 0, 64);
        if (total0 + running >= T) {
            unsigned long long mask = __ballot(s + running >= T);
            int m = 63 - __clzll(mask);
            unsigned sm = (unsigned)__shfl((int)s, m, 64);
            unsigned vm = (unsigned)__shfl((int)v, m, 64);
            if (lane == 0) { *outB = c * 64 + m; *outR = T - (sm + running - vm); }
            return;
        }
        running += total0;
        v = vn;
    }
    if (lane == 0) { *outB = 0; *outR = T; }
}

// ---------------- phase 2: top-512 select + decode-from-pred + LDS IoU + greedy scan ----------------
__device__ __forceinline__ void selnms_body(P2& S, int b, int t,
                                            const float* __restrict__ pred,
                                            const float* __restrict__ scores,
                                            const unsigned* __restrict__ wmaxg,
                                            float* __restrict__ out) {
    if (t == 0) { S.S_cnt = 0; S.S_ecnt = 0; S.S_done = 0; }
    // conf = min(0.25, max score); batched loads (9 independent) then reduce
    if (t < 64) {
        unsigned tmp[9];
#pragma unroll
        for (int k = 0; k < 9; k++) {
            int i = t + k * 64;
            tmp[k] = (i < NWV) ? wmaxg[b * NWV + i] : 0u;
        }
        unsigned m = 0;
#pragma unroll
        for (int k = 0; k < 9; k++) if (tmp[k] > m) m = tmp[k];
        for (int off = 32; off > 0; off >>= 1) {
            unsigned o = (unsigned)__shfl_down((int)m, off, 64);
            if (o > m) m = o;
        }
        if (t == 0) { S.S_conf = fminf(0.25f, __uint_as_float(m)); S.S_mbits = m; }
    }
    for (int i = t; i < 2048; i += 1024) { S.histA[i] = 0; S.histB[i] = 0; }
    for (int i = t; i < KPRE * 8; i += 1024) S.siou[i] = 0ull;
    if (t < 256) S.elist64[t] = 0ull;     // zero so boundary rank can scan all 256 branchlessly
    __syncthreads();
    float conf = S.S_conf;
    // key build (registers) + pass-A histogram in ONE sweep
    const float4* sc4 = (const float4*)(scores + (size_t)b * NN);
    unsigned ka[8];
    unsigned kb[4] = {0u, 0u, 0u, 0u};
    {
        float4 u0 = sc4[2 * t], u1 = sc4[2 * t + 1];
        ka[0] = (u0.x >= conf) ? __float_as_uint(u0.x) : 0u;
        ka[1] = (u0.y >= conf) ? __float_as_uint(u0.y) : 0u;
        ka[2] = (u0.z >= conf) ? __float_as_uint(u0.z) : 0u;
        ka[3] = (u0.w >= conf) ? __float_as_uint(u0.w) : 0u;
        ka[4] = (u1.x >= conf) ? __float_as_uint(u1.x) : 0u;
        ka[5] = (u1.y >= conf) ? __float_as_uint(u1.y) : 0u;
        ka[6] = (u1.z >= conf) ? __float_as_uint(u1.z) : 0u;
        ka[7] = (u1.w >= conf) ? __float_as_uint(u1.w) : 0u;
        if (t < 52) {                     // tail anchors 8192..8399
            float4 u2 = sc4[2048 + t];
            kb[0] = (u2.x >= conf) ? __float_as_uint(u2.x) : 0u;
            kb[1] = (u2.y >= conf) ? __float_as_uint(u2.y) : 0u;
            kb[2] = (u2.z >= conf) ? __float_as_uint(u2.z) : 0u;
            kb[3] = (u2.w >= conf) ? __float_as_uint(u2.w) : 0u;
        }
#pragma unroll
        for (int j = 0; j < 8; j++) atomicAdd(&S.histA[ka[j] >> 21], 1u);
        if (t < 52) {
#pragma unroll
            for (int j = 0; j < 4; j++) atomicAdd(&S.histA[kb[j] >> 21], 1u);
        }
    }
    __syncthreads();
    if (t < 64) {
        int cs = (int)(S.S_mbits >> 27); if (cs > 31) cs = 31;
        find_bin(S.histA, cs, 512u, t, &S.S_B[0], &S.S_T[0]);
    }
    __syncthreads();
    int B1 = S.S_B[0]; unsigned R1 = S.S_T[0];
    // pass B: bits[20:10] within top11==B1 (register sweep)
#pragma unroll
    for (int j = 0; j < 8; j++) {
        unsigned k = ka[j];
        if ((int)(k >> 21) == B1) atomicAdd(&S.histB[(k >> 10) & 0x7FFu], 1u);
    }
    if (t < 52) {
#pragma unroll
        for (int j = 0; j < 4; j++) {
            unsigned k = kb[j];
            if ((int)(k >> 21) == B1) atomicAdd(&S.histB[(k >> 10) & 0x7FFu], 1u);
        }
    }
    __syncthreads();
    if (t < 64) find_bin(S.histB, 31, R1, t, &S.S_B[1], &S.S_T[1]);
    __syncthreads();
    unsigned P = ((unsigned)B1 << 11) | (unsigned)S.S_B[1];
    unsigned R2 = S.S_T[1];
    // compact definite winners (top-22 > P); boundary bin (== P) kept as full keys
#pragma unroll
    for (int j = 0; j < 8; j++) {
        unsigned k = ka[j];
        unsigned n = 8u * (unsigned)t + (unsigned)j;
        if ((k >> 10) > P) {
            int pos = atomicAdd(&S.S_cnt, 1);
            S.list[pos] = ((unsigned long long)k << 32) | (unsigned long long)(unsigned)(~n);
        } else if (P != 0u && (k >> 10) == P) {
            int ep = atomicAdd(&S.S_ecnt, 1);
            if (ep < 256) S.elist64[ep] = ((unsigned long long)k << 32) | (unsigned long long)(unsigned)(~n);
        }
    }
    if (t < 52) {
#pragma unroll
        for (int j = 0; j < 4; j++) {
            unsigned k = kb[j];
            unsigned n = 8192u + 4u * (unsigned)t + (unsigned)j;
            if ((k >> 10) > P) {
                int pos = atomicAdd(&S.S_cnt, 1);
                S.list[pos] = ((unsigned long long)k << 32) | (unsigned long long)(unsigned)(~n);
            } else if (P != 0u && (k >> 10) == P) {
                int ep = atomicAdd(&S.S_ecnt, 1);
                if (ep < 256) S.elist64[ep] = ((unsigned long long)k << 32) | (unsigned long long)(unsigned)(~n);
            }
        }
    }
    __syncthreads();
    // boundary: top-R2 of the 22-bit-tied entries by full (key,~idx) order.
    // elist zero-padded -> branchless 256-scan with pipelined b128 LDS reads.
    int ecnt = S.S_ecnt; if (ecnt > 256) ecnt = 256;
    if (t < ecnt) {
        unsigned long long my = S.elist64[t];
        const ulonglong2* e2 = (const ulonglong2*)S.elist64;
        int r = 0;
#pragma unroll 4
        for (int j = 0; j < 128; j += 4) {
            ulonglong2 a = e2[j], b2 = e2[j + 1], c2 = e2[j + 2], d2 = e2[j + 3];
            r += (int)(a.x > my) + (int)(a.y > my) + (int)(b2.x > my) + (int)(b2.y > my);
            r += (int)(c2.x > my) + (int)(c2.y > my) + (int)(d2.x > my) + (int)(d2.y > my);
        }
        if (r < (int)R2) {
            int pos = atomicAdd(&S.S_cnt, 1);
            S.list[pos] = my;
        }
    }
    __syncthreads();
    int nval = S.S_cnt;                   // == 512 unless fewer valid
    for (int i = nval + t; i < KPRE; i += 1024) S.list[i] = 0ull;
    __syncthreads();
    // exact rank: split j-range across both thread-halves, b128 reads, 8 keys/step
    {
        int tt = t & 511, half = t >> 9;
        unsigned long long K0 = S.list[tt];
        const ulonglong2* l2 = (const ulonglong2*)S.list;
        int jb = half * 128;
        int r0 = 0;
#pragma unroll 4
        for (int j = 0; j < 128; j += 4) {
            ulonglong2 a = l2[jb + j], b2 = l2[jb + j + 1], c2 = l2[jb + j + 2], d2 = l2[jb + j + 3];
            r0 += (int)(a.x > K0) + (int)(a.y > K0) + (int)(b2.x > K0) + (int)(b2.y > K0);
            r0 += (int)(c2.x > K0) + (int)(c2.y > K0) + (int)(d2.x > K0) + (int)(d2.y > K0);
        }
        if (half) S.srank[tt] = r0;
        __syncthreads();
        if (!half) {
            int r = r0 + S.srank[tt];
            if (K0 != 0ull) S.sorted[r] = K0; else S.sorted[tt] = 0ull;
        }
    }
    __syncthreads();
    // gather + decode directly from pred (L3-warm); identical f32 ops -> bit-exact
    if (t < KPRE) {
        unsigned long long key = S.sorted[t];
        int valid = ((unsigned)(key >> 32)) != 0u;
        unsigned n = ~(unsigned)key;
        if (!valid) n = 0;
        const float* pr = pred + ((size_t)b * NN + n) * 85;
        float cx = pr[0], cy = pr[1], bw = pr[2], bh = pr[3], obj = pr[4];
        float cc = pr[5]; int cp = 0;
        for (int c = 1; c < NC; c++) {
            float v = pr[5 + c];
            if (v > cc) { cc = v; cp = c; }       // strict >: first max, matches argmax
        }
        float hw = __fmul_rn(bw, 0.5f), hh = __fmul_rn(bh, 0.5f);
        float x1 = cx - hw, y1 = cy - hh, x2 = cx + hw, y2 = cy + hh;
        float off = __fmul_rn((float)cp, 4096.0f);
        float4 bo = make_float4(x1 + off, y1 + off, x2 + off, y2 + off);
        S.sraw[t] = make_float4(x1, y1, x2, y2);
        S.sb[t] = bo;
        S.smeta[t] = make_float4(obj, cc, (float)cp, valid ? 1.0f : 0.0f);
        S.sarea[t] = __fmul_rn(bo.z - bo.x, bo.w - bo.y);
    }
    __syncthreads();

    // ---- chunked IoU build + sequential greedy scan with early exit ----
    unsigned long long keepW = 0ull;
    int cnt = 0;
    int lg = t >> 3, lw = t & 7;
    int irow = t >> 4, iq = t & 15;               // IoU: 16 threads per row

    for (int c = 0; c < 8; c++) {
        int row = (c << 6) + irow;
        float4 bi = S.sb[row];
        float ai = S.sarea[row];
        for (int k = 0; k <= c; k++) {            // triangle only
            unsigned long long wk = 0ull;
            int j0 = (k << 6) + iq;
#pragma unroll
            for (int s = 0; s < 4; s++) {
                int j = j0 + (s << 4);
                float4 bj = S.sb[j];
                float xx1 = fmaxf(bi.x, bj.x);
                float yy1 = fmaxf(bi.y, bj.y);
                float xx2 = fminf(bi.z, bj.z);
                float yy2 = fminf(bi.w, bj.w);
                float iw = fmaxf(xx2 - xx1, 0.0f);
                float ih = fmaxf(yy2 - yy1, 0.0f);
                float inter = __fmul_rn(iw, ih);
                float uni = (ai + S.sarea[j]) - inter;
                float iou = inter / (uni + 1e-9f);
                if (iou > 0.45f && j < row) wk |= 1ull << (j & 63);
            }
            if (wk) atomicOr(&S.siou[(row << 3) + k], wk);
        }
        __syncthreads();
        if (t < 64) {
            unsigned long long R[8];
#pragma unroll
            for (int k = 0; k < 8; k++) R[k] = S.siou[(c << 9) + (k << 6) + t];
#pragma unroll
            for (int k = 0; k < 8; k++) {
#pragma unroll
                for (int m = 0; m < 8; m++) {
                    int ii = (c << 6) + (k << 3) + m;
                    bool hit = (lg == m) && ((R[k] & keepW) != 0ull);
                    unsigned long long bal = __ballot(hit);
                    bool kept = (bal == 0ull) && (ii < nval);
                    if (kept) {
                        cnt++;
                        if (lw == c) keepW |= 1ull << ((k << 3) + m);
                    }
                }
            }
            if (t == 0) S.S_done = (cnt >= MAXOUT) ? 1 : 0;
        }
        __syncthreads();
        if (S.S_done) break;                      // first-100-kept set is final
    }
    if (t < 8) S.skeep[t] = keepW;
    __syncthreads();

    // ---- output ----
    float* dets = out + (size_t)b * (MAXOUT * 7);
    float* maskp = out + (size_t)NB * MAXOUT * 7 + (size_t)b * MAXOUT;
    for (int m = t; m < MAXOUT * 7; m += 1024) dets[m] = 0.0f;
    for (int m = t; m < MAXOUT; m += 1024) maskp[m] = 0.0f;
    __syncthreads();
    if (t < KPRE) {
        int wq = t >> 6;
        unsigned long long kw = S.skeep[wq];
        if ((kw >> (t & 63)) & 1ull) {
            int rank = __popcll(kw & ((1ull << (t & 63)) - 1ull));
            for (int w2 = 0; w2 < wq; w2++) rank += __popcll(S.skeep[w2]);
            if (rank < MAXOUT) {
                float4 rb = S.sraw[t];
                float4 mt = S.smeta[t];
                float* rowp = dets + rank * 7;
                rowp[0] = rb.x; rowp[1] = rb.y; rowp[2] = rb.z; rowp[3] = rb.w;
                rowp[4] = mt.x; rowp[5] = mt.y; rowp[6] = mt.z;
                maskp[rank] = 1.0f;
            }
        }
    }
}

// ---------------- fused cooperative kernel ----------------
__global__ __launch_bounds__(1024) void fused_kernel(const float* __restrict__ pred,
                                                     float* __restrict__ scores,
                                                     unsigned* __restrict__ wmaxg,
                                                     float* __restrict__ out) {
    __shared__ SMem sm;
    int t = threadIdx.x;
    int w = t >> 6, lane = t & 63;
    int wid = blockIdx.x * 16 + w;
    int nw = gridDim.x * 16;
    const float4* p4 = (const float4*)pred;
    for (int gg = wid; gg < NGROUPS; gg += nw)
        score_group(p4, gg, w, lane, sm.stg, scores, wmaxg);
    cg::this_grid().sync();
    if (blockIdx.x < NB)
        selnms_body(sm.p2, blockIdx.x, t, pred, scores, wmaxg, out);
}

// ---------------- fallback (if cooperative launch is rejected under capture) ----------------
__global__ __launch_bounds__(1024) void score2_kernel(const float* __restrict__ pred,
                                                      float* __restrict__ scores,
                                                      unsigned* __restrict__ wmaxg) {
    __shared__ SMem sm;
    int t = threadIdx.x;
    int w = t >> 6, lane = t & 63;
    int wid = blockIdx.x * 16 + w;
    int nw = gridDim.x * 16;
    const float4* p4 = (const float4*)pred;
    for (int gg = wid; gg < NGROUPS; gg += nw)
        score_group(p4, gg, w, lane, sm.stg, scores, wmaxg);
}

__global__ __launch_bounds__(1024) void selnms2_kernel(const float* __restrict__ pred,
                                                       const float* __restrict__ scores,
                                                       const unsigned* __restrict__ wmaxg,
                                                       float* __restrict__ out) {
    __shared__ SMem sm;
    selnms_body(sm.p2, blockIdx.x, threadIdx.x, pred, scores, wmaxg, out);
}

extern "C" void kernel_launch(void* const* d_in, const int* in_sizes, int n_in,
                              void* d_out, int out_size, void* d_ws, size_t ws_size,
                              hipStream_t stream) {
    const float* pred = (const float*)d_in[0];
    float* out = (float*)d_out;

    char* ws = (char*)d_ws;
    unsigned* wmaxg = (unsigned*)ws;                  // 16832*4 = 67,328 -> pad 67,584
    float* scores = (float*)(ws + 67584);             // 32*8400*4 = 1,075,200 -> 1,142,784

    void* args[4] = { (void*)&pred, (void*)&scores, (void*)&wmaxg, (void*)&out };
    hipError_t err = hipLaunchCooperativeKernel(fused_kernel, dim3(GRID1), dim3(1024),
                                                args, 0, stream);
    if (err != hipSuccess) {
        (void)hipGetLastError();                      // clear error state
        score2_kernel<<<256, 1024, 0, stream>>>(pred, scores, wmaxg);
        selnms2_kernel<<<NB, 1024, 0, stream>>>(pred, scores, wmaxg, out);
    }
}

// Round 4
// 167.650 us; speedup vs baseline: 1.2895x; 1.2895x over previous
//
#include <hip/hip_runtime.h>

#define NB 32
#define NN 8400
#define NC 80
#define KPRE 512
#define MAXOUT 100
#define NGRP 263   // score blocks per image; block = 2 waves x 16 rows
#define NWV 526    // wave-groups per image (per-wave maxima)

// ---------------- Kernel A: scores + per-anchor decode + per-WAVE max (no barrier) ----------------
// Each wave stages 16 rows (340 float4 = 5.4 KB); block LDS 10.9 KB -> 14 blocks/CU.
// 4 lanes share a row: q=lane&3 scans classes 20q..20q+19; two shfl_xor steps combine.
__global__ __launch_bounds__(128) void score_kernel(const float* __restrict__ pred,
                                                    float* __restrict__ scores,
                                                    unsigned* __restrict__ wmaxg,
                                                    float4* __restrict__ rawbox,
                                                    float4* __restrict__ minfo) {
    int b = blockIdx.y;
    int w = threadIdx.x >> 6, lane = threadIdx.x & 63;
    int g = blockIdx.x * 2 + w;                    // 16-row group in image (0..524 valid; 525 = pad)
    __shared__ float4 stg4[2][340];                // 16 rows x 85 floats per wave
    const float4* p4 = (const float4*)pred;
    size_t base4 = (size_t)b * 178500 + (size_t)g * 340;
    size_t img_end4 = ((size_t)b + 1) * 178500;
    for (int k = lane; k < 340; k += 64) {
        size_t e = base4 + k;
        if (e >= img_end4) e = img_end4 - 1;       // clamp tail (invalid groups discarded below)
        stg4[w][k] = p4[e];
    }
    // no cross-wave LDS sharing -> no barrier needed (compiler waits lgkmcnt within wave)
    int rl = lane >> 2, q = lane & 3;
    int row = g * 16 + rl;
    const float* r = (const float*)&stg4[w][0] + rl * 85;
    float cx = r[0], cy = r[1], bw = r[2], bh = r[3], obj = r[4];
    int c0 = 5 + q * 20;
    float cc = r[c0];
    int cp = q * 20;
    for (int c = 1; c < 20; c++) {
        float v = r[c0 + c];
        if (v > cc) { cc = v; cp = q * 20 + c; }   // strict >: first-max within quarter
    }
    // combine 4-lane group; tie -> lower class index
    {
        float cc1 = __shfl_xor(cc, 1, 64); int cp1 = __shfl_xor(cp, 1, 64);
        bool take = (cc1 > cc) || (cc1 == cc && cp1 < cp);
        cc = take ? cc1 : cc; cp = take ? cp1 : cp;
        float cc2 = __shfl_xor(cc, 2, 64); int cp2 = __shfl_xor(cp, 2, 64);
        take = (cc2 > cc) || (cc2 == cc && cp2 < cp);
        cc = take ? cc2 : cc; cp = take ? cp2 : cp;
    }
    float s = __fmul_rn(obj, cc);
    float hw = __fmul_rn(bw, 0.5f), hh = __fmul_rn(bh, 0.5f);
    float x1 = cx - hw, y1 = cy - hh, x2 = cx + hw, y2 = cy + hh;
    // redistribute: lane l<16 takes row l's result (lives in lane 4l), coalesced writes
    int srcl = (lane & 15) * 4;
    float v0 = __shfl(x1, srcl, 64);
    float v1 = __shfl(y1, srcl, 64);
    float v2 = __shfl(x2, srcl, 64);
    float v3 = __shfl(y2, srcl, 64);
    float v4 = __shfl(obj, srcl, 64);
    float v5 = __shfl(cc, srcl, 64);
    int   v6 = __shfl(cp, srcl, 64);
    float v7 = __shfl(s, srcl, 64);
    int wrow = g * 16 + (lane & 15);
    if (lane < 16 && wrow < NN) {
        size_t idx = (size_t)b * NN + wrow;
        scores[idx] = v7;
        rawbox[idx] = make_float4(v0, v1, v2, v3);
        minfo[idx]  = make_float4(v4, v5, (float)v6, v7);
    }
    // per-wave max (invalid rows -> 0); every wmaxg slot written -> no init needed
    if (row >= NN) s = 0.0f;
    unsigned bits = __float_as_uint(s);
    for (int o = 32; o > 0; o >>= 1) {
        unsigned other = (unsigned)__shfl_down((int)bits, o, 64);
        if (other > bits) bits = other;
    }
    if (lane == 0) wmaxg[b * NWV + g] = bits;
}

// ---- wave-0 helper: largest bin B with suffix(B) >= T; R = T - suffix(B+1).
// Prefetches the next chunk's LDS row so the load hides under the 6-step shfl chain.
__device__ __forceinline__ void find_bin(const unsigned* hist, int cstart, unsigned T, int lane,
                                         int* outB, unsigned* outR) {
    unsigned running = 0;
    unsigned v = hist[cstart * 64 + lane];
    for (int c = cstart; c >= 0; c--) {
        unsigned vn = (c > 0) ? hist[(c - 1) * 64 + lane] : 0u;   // prefetch next chunk
        unsigned s = v;
        for (int off = 1; off < 64; off <<= 1) {
            unsigned u = (unsigned)__shfl_down((int)s, off, 64);
            if (lane + off < 64) s += u;
        }
        unsigned total0 = (unsigned)__shfl((int)s, 0, 64);
        if (total0 + running >= T) {
            unsigned long long mask = __ballot(s + running >= T);
            int m = 63 - __clzll(mask);
            unsigned sm = (unsigned)__shfl((int)s, m, 64);
            unsigned vm = (unsigned)__shfl((int)v, m, 64);
            if (lane == 0) { *outB = c * 64 + m; *outR = T - (sm + running - vm); }
            return;
        }
        running += total0;
        v = vn;
    }
    if (lane == 0) { *outB = 0; *outR = T; }   // fewer than T valid keys in range
}

// ---------------- Fused Kernel B+C+D: top-512 select + LDS-resident IoU + greedy scan + output ----
// One block per image (32 blocks, 1024 threads, ~88 KB LDS).
// IoU bitmatrix built chunk-by-chunk (64 rows), interleaved with the sequential greedy scan,
// EARLY EXIT once MAXOUT kept (suppressed boxes never suppress others -> first-100-kept is final).
__global__ __launch_bounds__(1024) void selnms_kernel(const float* __restrict__ scores,
                                                      const unsigned* __restrict__ wmaxg,
                                                      const float4* __restrict__ rawbox,
                                                      const float4* __restrict__ minfo,
                                                      float* __restrict__ out) {
    int b = blockIdx.x, t = threadIdx.x;
    int lane = t & 63;
    __shared__ unsigned histA[2048];              // 8 KB
    __shared__ unsigned histB[2048];              // 8 KB
    __shared__ unsigned long long list[KPRE];     // 4 KB
    __shared__ unsigned long long sorted[KPRE];   // 4 KB
    __shared__ unsigned long long elist64[256];   // 2 KB
    __shared__ int srank[KPRE];                   // 2 KB
    __shared__ float4 sb[KPRE];                   // 8 KB  offset boxes
    __shared__ float4 sraw[KPRE];                 // 8 KB  raw boxes
    __shared__ float4 smeta[KPRE];                // 8 KB  (obj, cc, cp, valid)
    __shared__ float  sarea[KPRE];                // 2 KB  box areas
    __shared__ unsigned long long siou[KPRE * 8]; // 32 KB IoU bitmatrix
    __shared__ unsigned long long skeep[8];
    __shared__ int S_B[2];
    __shared__ unsigned S_T[2];
    __shared__ int S_cnt, S_ecnt, S_done;
    __shared__ float S_conf;
    __shared__ unsigned S_mbits;

    if (t == 0) { S_cnt = 0; S_ecnt = 0; S_done = 0; }
    // conf = min(0.25, max score): batched independent loads then wave reduce
    if (t < 64) {
        unsigned tmp[9];
#pragma unroll
        for (int k = 0; k < 9; k++) {
            int i = t + k * 64;
            tmp[k] = (i < NWV) ? wmaxg[b * NWV + i] : 0u;
        }
        unsigned m = 0;
#pragma unroll
        for (int k = 0; k < 9; k++) if (tmp[k] > m) m = tmp[k];
        for (int off = 32; off > 0; off >>= 1) {
            unsigned o = (unsigned)__shfl_down((int)m, off, 64);
            if (o > m) m = o;
        }
        if (t == 0) { S_conf = fminf(0.25f, __uint_as_float(m)); S_mbits = m; }
    }
    for (int i = t; i < 2048; i += 1024) { histA[i] = 0; histB[i] = 0; }
    for (int i = t; i < KPRE * 8; i += 1024) siou[i] = 0ull;
    if (t < 256) elist64[t] = 0ull;               // zero-pad so boundary rank scans branchlessly
    __syncthreads();
    float conf = S_conf;
    // key build (registers) + pass-A histogram in ONE sweep
    const float4* sc4 = (const float4*)(scores + (size_t)b * NN);
    unsigned ka[8];
    unsigned kb[4] = {0u, 0u, 0u, 0u};
    {
        float4 u0 = sc4[2 * t], u1 = sc4[2 * t + 1];
        ka[0] = (u0.x >= conf) ? __float_as_uint(u0.x) : 0u;
        ka[1] = (u0.y >= conf) ? __float_as_uint(u0.y) : 0u;
        ka[2] = (u0.z >= conf) ? __float_as_uint(u0.z) : 0u;
        ka[3] = (u0.w >= conf) ? __float_as_uint(u0.w) : 0u;
        ka[4] = (u1.x >= conf) ? __float_as_uint(u1.x) : 0u;
        ka[5] = (u1.y >= conf) ? __float_as_uint(u1.y) : 0u;
        ka[6] = (u1.z >= conf) ? __float_as_uint(u1.z) : 0u;
        ka[7] = (u1.w >= conf) ? __float_as_uint(u1.w) : 0u;
        if (t < 52) {                              // tail anchors 8192..8399
            float4 u2 = sc4[2048 + t];
            kb[0] = (u2.x >= conf) ? __float_as_uint(u2.x) : 0u;
            kb[1] = (u2.y >= conf) ? __float_as_uint(u2.y) : 0u;
            kb[2] = (u2.z >= conf) ? __float_as_uint(u2.z) : 0u;
            kb[3] = (u2.w >= conf) ? __float_as_uint(u2.w) : 0u;
        }
#pragma unroll
        for (int j = 0; j < 8; j++) atomicAdd(&histA[ka[j] >> 21], 1u);
        if (t < 52) {
#pragma unroll
            for (int j = 0; j < 4; j++) atomicAdd(&histA[kb[j] >> 21], 1u);
        }
    }
    __syncthreads();
    if (t < 64) {
        int cs = (int)(S_mbits >> 27); if (cs > 31) cs = 31;
        find_bin(histA, cs, 512u, t, &S_B[0], &S_T[0]);
    }
    __syncthreads();
    int B1 = S_B[0]; unsigned R1 = S_T[0];
    // pass B: bits[20:10] within top11==B1 (register sweep)
#pragma unroll
    for (int j = 0; j < 8; j++) {
        unsigned k = ka[j];
        if ((int)(k >> 21) == B1) atomicAdd(&histB[(k >> 10) & 0x7FFu], 1u);
    }
    if (t < 52) {
#pragma unroll
        for (int j = 0; j < 4; j++) {
            unsigned k = kb[j];
            if ((int)(k >> 21) == B1) atomicAdd(&histB[(k >> 10) & 0x7FFu], 1u);
        }
    }
    __syncthreads();
    if (t < 64) find_bin(histB, 31, R1, t, &S_B[1], &S_T[1]);
    __syncthreads();
    unsigned P = ((unsigned)B1 << 11) | (unsigned)S_B[1];
    unsigned R2 = S_T[1];
    // compact definite winners (top-22 > P); boundary bin (== P) as full keys.
    // wave-aggregated LDS atomics: one ballot + leader atomicAdd per wave per key slot.
    unsigned long long ltmask = (1ull << lane) - 1ull;
#pragma unroll
    for (int j = 0; j < 8; j++) {
        unsigned k = ka[j];
        unsigned n = 8u * (unsigned)t + (unsigned)j;
        unsigned long long key = ((unsigned long long)k << 32) | (unsigned long long)(unsigned)(~n);
        bool win = (k >> 10) > P;
        bool tie = (P != 0u) && ((k >> 10) == P);
        unsigned long long mw = __ballot(win);
        unsigned long long mtie = __ballot(tie);
        int baseW = 0, baseT = 0;
        if (lane == 0) {
            if (mw)   baseW = atomicAdd(&S_cnt, __popcll(mw));
            if (mtie) baseT = atomicAdd(&S_ecnt, __popcll(mtie));
        }
        baseW = __shfl(baseW, 0, 64);
        baseT = __shfl(baseT, 0, 64);
        if (win) {
            list[baseW + __popcll(mw & ltmask)] = key;
        } else if (tie) {
            int ep = baseT + __popcll(mtie & ltmask);
            if (ep < 256) elist64[ep] = key;
        }
    }
    if (t < 52) {
#pragma unroll
        for (int j = 0; j < 4; j++) {
            unsigned k = kb[j];
            unsigned n = 8192u + 4u * (unsigned)t + (unsigned)j;
            unsigned long long key = ((unsigned long long)k << 32) | (unsigned long long)(unsigned)(~n);
            bool win = (k >> 10) > P;
            bool tie = (P != 0u) && ((k >> 10) == P);
            unsigned long long mw = __ballot(win);
            unsigned long long mtie = __ballot(tie);
            int baseW = 0, baseT = 0;
            if (lane == 0) {
                if (mw)   baseW = atomicAdd(&S_cnt, __popcll(mw));
                if (mtie) baseT = atomicAdd(&S_ecnt, __popcll(mtie));
            }
            baseW = __shfl(baseW, 0, 64);
            baseT = __shfl(baseT, 0, 64);
            if (win) {
                list[baseW + __popcll(mw & ltmask)] = key;
            } else if (tie) {
                int ep = baseT + __popcll(mtie & ltmask);
                if (ep < 256) elist64[ep] = key;
            }
        }
    }
    __syncthreads();
    // boundary: top-R2 of the 22-bit-tied entries by full (key,~idx) order.
    // elist zero-padded -> branchless 256-scan with b128 wave-uniform reads.
    int ecnt = S_ecnt; if (ecnt > 256) ecnt = 256;
    if (t < ecnt) {
        unsigned long long my = elist64[t];
        const ulonglong2* e2 = (const ulonglong2*)elist64;
        int r = 0;
#pragma unroll 4
        for (int j = 0; j < 128; j += 4) {
            ulonglong2 a = e2[j], b2 = e2[j + 1], c2 = e2[j + 2], d2 = e2[j + 3];
            r += (int)(a.x > my) + (int)(a.y > my) + (int)(b2.x > my) + (int)(b2.y > my);
            r += (int)(c2.x > my) + (int)(c2.y > my) + (int)(d2.x > my) + (int)(d2.y > my);
        }
        if (r < (int)R2) {
            int pos = atomicAdd(&S_cnt, 1);
            list[pos] = my;
        }
    }
    __syncthreads();
    int nval = S_cnt;                              // == 512 unless fewer valid
    for (int i = nval + t; i < KPRE; i += 1024) list[i] = 0ull;
    __syncthreads();
    // exact rank: split j-range across both thread-halves, b128 wave-uniform reads, 8 keys/step
    {
        int tt = t & 511, half = t >> 9;
        unsigned long long K0 = list[tt];
        const ulonglong2* l2 = (const ulonglong2*)list;
        int jb = half * 128;
        int r0 = 0;
#pragma unroll 4
        for (int j = 0; j < 128; j += 4) {
            ulonglong2 a = l2[jb + j], b2 = l2[jb + j + 1], c2 = l2[jb + j + 2], d2 = l2[jb + j + 3];
            r0 += (int)(a.x > K0) + (int)(a.y > K0) + (int)(b2.x > K0) + (int)(b2.y > K0);
            r0 += (int)(c2.x > K0) + (int)(c2.y > K0) + (int)(d2.x > K0) + (int)(d2.y > K0);
        }
        if (half) srank[tt] = r0;
        __syncthreads();
        if (!half) {
            int r = r0 + srank[tt];
            if (K0 != 0ull) sorted[r] = K0; else sorted[tt] = 0ull;
        }
    }
    __syncthreads();
    // tiny gather: two float4 loads per row (decode already done in score_kernel)
    if (t < KPRE) {
        unsigned long long key = sorted[t];
        int valid = ((unsigned)(key >> 32)) != 0u;
        unsigned n = ~(unsigned)key;
        if (!valid) n = 0;
        size_t src = (size_t)b * NN + n;
        float4 rb = rawbox[src];
        float4 mi = minfo[src];
        float off = __fmul_rn(mi.z, 4096.0f);
        float4 bo = make_float4(rb.x + off, rb.y + off, rb.z + off, rb.w + off);
        sraw[t] = rb;
        sb[t] = bo;
        smeta[t] = make_float4(mi.x, mi.y, mi.z, valid ? 1.0f : 0.0f);
        sarea[t] = __fmul_rn(bo.z - bo.x, bo.w - bo.y);
    }
    __syncthreads();

    // ---- chunked IoU build + sequential greedy scan with early exit ----
    unsigned long long keepW = 0ull;
    int cnt = 0;
    int lg = t >> 3, lw = t & 7;
    int irow = t >> 4, iq = t & 15;                // IoU: 16 threads per row

    for (int c = 0; c < 8; c++) {
        int row = (c << 6) + irow;
        float4 bi = sb[row];
        float ai = sarea[row];
        for (int k = 0; k <= c; k++) {             // triangle only
            unsigned long long wk = 0ull;
            int j0 = (k << 6) + iq;
#pragma unroll
            for (int s = 0; s < 4; s++) {
                int j = j0 + (s << 4);
                float4 bj = sb[j];
                float xx1 = fmaxf(bi.x, bj.x);
                float yy1 = fmaxf(bi.y, bj.y);
                float xx2 = fminf(bi.z, bj.z);
                float yy2 = fminf(bi.w, bj.w);
                float iw = fmaxf(xx2 - xx1, 0.0f);
                float ih = fmaxf(yy2 - yy1, 0.0f);
                float inter = __fmul_rn(iw, ih);
                float uni = (ai + sarea[j]) - inter;
                float iou = inter / (uni + 1e-9f);
                if (iou > 0.45f && j < row) wk |= 1ull << (j & 63);
            }
            if (wk) atomicOr(&siou[(row << 3) + k], wk);
        }
        __syncthreads();
        if (t < 64) {
            unsigned long long R[8];
#pragma unroll
            for (int k = 0; k < 8; k++) R[k] = siou[(c << 9) + (k << 6) + t];
#pragma unroll
            for (int k = 0; k < 8; k++) {
#pragma unroll
                for (int m = 0; m < 8; m++) {
                    int ii = (c << 6) + (k << 3) + m;
                    bool hit = (lg == m) && ((R[k] & keepW) != 0ull);
                    unsigned long long bal = __ballot(hit);
                    bool kept = (bal == 0ull) && (ii < nval);
                    if (kept) {
                        cnt++;
                        if (lw == c) keepW |= 1ull << ((k << 3) + m);
                    }
                }
            }
            if (t == 0) S_done = (cnt >= MAXOUT) ? 1 : 0;
        }
        __syncthreads();
        if (S_done) break;                         // first-100-kept set is final
    }
    if (t < 8) skeep[t] = keepW;
    __syncthreads();

    // ---- output ----
    float* dets = out + (size_t)b * (MAXOUT * 7);
    float* maskp = out + (size_t)NB * MAXOUT * 7 + (size_t)b * MAXOUT;
    for (int m = t; m < MAXOUT * 7; m += 1024) dets[m] = 0.0f;
    for (int m = t; m < MAXOUT; m += 1024) maskp[m] = 0.0f;
    __syncthreads();
    if (t < KPRE) {
        int wq = t >> 6;
        unsigned long long kw = skeep[wq];
        if ((kw >> (t & 63)) & 1ull) {
            int rank = __popcll(kw & ((1ull << (t & 63)) - 1ull));
            for (int w2 = 0; w2 < wq; w2++) rank += __popcll(skeep[w2]);
            if (rank < MAXOUT) {
                float4 rb = sraw[t];
                float4 mt = smeta[t];
                float* rowp = dets + rank * 7;
                rowp[0] = rb.x; rowp[1] = rb.y; rowp[2] = rb.z; rowp[3] = rb.w;
                rowp[4] = mt.x; rowp[5] = mt.y; rowp[6] = mt.z;
                maskp[rank] = 1.0f;
            }
        }
    }
}

extern "C" void kernel_launch(void* const* d_in, const int* in_sizes, int n_in,
                              void* d_out, int out_size, void* d_ws, size_t ws_size,
                              hipStream_t stream) {
    const float* pred = (const float*)d_in[0];
    float* out = (float*)d_out;

    char* ws = (char*)d_ws;
    unsigned* wmaxg = (unsigned*)ws;                  // 32*526*4 = 67,328 -> pad 67,584
    float* scores = (float*)(ws + 67584);             // 1,075,200 -> 1,142,784
    float4* rawbox = (float4*)(ws + 1142784);         // 4,300,800 -> 5,443,584
    float4* minfo  = (float4*)(ws + 5443584);         // 4,300,800 -> 9,744,384

    dim3 gA(NGRP, NB);
    score_kernel<<<gA, 128, 0, stream>>>(pred, scores, wmaxg, rawbox, minfo);
    selnms_kernel<<<NB, 1024, 0, stream>>>(scores, wmaxg, rawbox, minfo, out);
}